// Round 9
// baseline (429.589 us; speedup 1.0000x reference)
//
#include <hip/hip_runtime.h>
#include <hip/hip_bf16.h>

#define NROWS 65536
#define DDIM  2048
#define NEXP  8
#define THREADS 512
#define NBLOCKS 512
#define ROWS_PER_BLOCK (NROWS / NBLOCKS)        // 128
#define ROWS_PER_WAVE  (ROWS_PER_BLOCK / 8)     // 16 (8 waves/block)
#define PAIRS          (ROWS_PER_WAVE / 2)      // 8
#define KSTEPS         (DDIM / 256)             // 8
#define KBATCH 4                                 // k-steps per load batch

typedef float v4f __attribute__((ext_vector_type(4)));
typedef float v2f __attribute__((ext_vector_type(2)));

// Kernel A: gate scores -> masked softmax -> top1 prob. Writes (p, top1) to
// out[row*8 + {0,1}]; accumulates denom via LDS then 8 global atomics/block.
//
// R1-R8 lessons baked in:
//  - 512-thr blocks + 64 KiB LDS -> allocator caps at 128 VGPRs (2 blk/CU,
//    4 waves/SIMD); fits the live set. 1024-thr blocks -> 64-reg cap ->
//    spill (R2-R4). Cross-iteration cur/nxt pipelining -> 200 MB scratch
//    (R5). Occupancy is hard-capped at 16 waves/CU by the 128-VGPR budget,
//    so latency hiding must come from per-wave ILP:
//  - R9: batch 8 loads (KBATCH=4 k-steps x 2 rows) into registers BEFORE
//    consuming -> 8 KB in flight per wave instead of 2 KB; liveness stays
//    inside the macro-step (~75 regs), unlike R5's cross-iteration buffer.
//  - Non-temporal x loads (stream-once; don't evict w/out). ext_vector
//    types required for the nt builtins (R7).
__global__ __launch_bounds__(THREADS) void gate_kernel(
    const float* __restrict__ x,       // (B, D)
    const int*   __restrict__ label,   // (B,)
    const float* __restrict__ w,       // (D, E) row-major
    const float* __restrict__ bgate,   // (E,)
    float* __restrict__ out,           // (B, E)
    float* __restrict__ denom)         // (E,) pre-zeroed
{
    __shared__ float wt[NEXP * DDIM];  // 64 KiB, wt[e*D + d]
    __shared__ float dsum[NEXP];
    __shared__ float sbg[NEXP];

    const int tid = threadIdx.x;
    if (tid < NEXP) { dsum[tid] = 0.0f; sbg[tid] = bgate[tid]; }

    // Stage w transposed into LDS (coalesced float4 reads, 8 per thread).
    for (int i = tid; i < (DDIM * NEXP) / 4; i += THREADS) {
        v4f v = *reinterpret_cast<const v4f*>(w + 4 * (size_t)i);
        const int d0 = i >> 1;
        const int e0 = (i & 1) * 4;
        wt[(e0 + 0) * DDIM + d0] = v.x;
        wt[(e0 + 1) * DDIM + d0] = v.y;
        wt[(e0 + 2) * DDIM + d0] = v.z;
        wt[(e0 + 3) * DDIM + d0] = v.w;
    }
    __syncthreads();

    const int wave = tid >> 6;
    const int lane = tid & 63;
    const int wrow = blockIdx.x * ROWS_PER_BLOCK + wave * ROWS_PER_WAVE;
    const float* xb = x + (size_t)wrow * DDIM + lane * 4;

    for (int p = 0; p < PAIRS; ++p) {
        const int roff0 = (p * 2) * DDIM;
        const int roff1 = roff0 + DDIM;

        float acc0[NEXP], acc1[NEXP];
#pragma unroll
        for (int e = 0; e < NEXP; ++e) { acc0[e] = 0.0f; acc1[e] = 0.0f; }

#pragma unroll
        for (int kk = 0; kk < KSTEPS / KBATCH; ++kk) {
            // Issue all 8 loads of this macro-step back-to-back (8 KB/wave
            // in flight), then consume; compiler can start FMAs at vmcnt(6).
            v4f a[KBATCH], b[KBATCH];
#pragma unroll
            for (int k = 0; k < KBATCH; ++k) {
                a[k] = __builtin_nontemporal_load(
                    reinterpret_cast<const v4f*>(xb + roff0 + (kk * KBATCH + k) * 256));
                b[k] = __builtin_nontemporal_load(
                    reinterpret_cast<const v4f*>(xb + roff1 + (kk * KBATCH + k) * 256));
            }
#pragma unroll
            for (int k = 0; k < KBATCH; ++k) {
#pragma unroll
                for (int e = 0; e < NEXP; ++e) {
                    const v4f wv = *reinterpret_cast<const v4f*>(
                        &wt[e * DDIM + (kk * KBATCH + k) * 256 + lane * 4]);
                    acc0[e] += a[k].x * wv.x + a[k].y * wv.y + a[k].z * wv.z + a[k].w * wv.w;
                    acc1[e] += b[k].x * wv.x + b[k].y * wv.y + b[k].z * wv.z + b[k].w * wv.w;
                }
            }
        }

        // Per-row: butterfly reduce, then epilogue (keeps live set small).
#pragma unroll
        for (int r = 0; r < 2; ++r) {
            const int row = wrow + p * 2 + r;
            float s[NEXP];
#pragma unroll
            for (int e = 0; e < NEXP; ++e) {
                float v = r ? acc1[e] : acc0[e];
#pragma unroll
                for (int m = 32; m >= 1; m >>= 1)
                    v += __shfl_xor(v, m, 64);
                s[e] = v + sbg[e];
            }

            float mA = s[0]; int aA = 0;
            if (s[1] > mA) { mA = s[1]; aA = 1; }
            if (s[2] > mA) { mA = s[2]; aA = 2; }
            if (s[3] > mA) { mA = s[3]; aA = 3; }
            const float sumA = __expf(s[0] - mA) + __expf(s[1] - mA) +
                               __expf(s[2] - mA) + __expf(s[3] - mA);
            float mB = s[4]; int aB = 4;
            if (s[5] > mB) { mB = s[5]; aB = 5; }
            if (s[6] > mB) { mB = s[6]; aB = 6; }
            if (s[7] > mB) { mB = s[7]; aB = 7; }
            const float sumB = __expf(s[4] - mB) + __expf(s[5] - mB) +
                               __expf(s[6] - mB) + __expf(s[7] - mB);

            const int   lab = label[row];
            const int   arg = lab ? aB : aA;
            const float pv  = 1.0f / (lab ? sumB : sumA);

            if (lane == 0) {
                v2f o; o.x = pv; o.y = (float)arg;
                __builtin_nontemporal_store(
                    o, reinterpret_cast<v2f*>(out + (size_t)row * NEXP));
                atomicAdd(&dsum[arg], pv);
            }
        }
    }

    __syncthreads();
    if (tid < NEXP) atomicAdd(&denom[tid], dsum[tid]);
}

// Kernel B: out[row, e] = (e==top1) ? p/(denom[e]+eps)*B : 0
__global__ __launch_bounds__(256) void finalize_kernel(
    float* __restrict__ out, const float* __restrict__ denom)
{
    const int row = blockIdx.x * blockDim.x + threadIdx.x;
    if (row >= NROWS) return;
    const float p = out[(size_t)row * NEXP + 0];
    const int   a = (int)out[(size_t)row * NEXP + 1];
    const float val = p / (denom[a] + 1e-6f) * 65536.0f;

    float vals[NEXP];
#pragma unroll
    for (int e = 0; e < NEXP; ++e) vals[e] = (e == a) ? val : 0.0f;

    v4f o0; o0.x = vals[0]; o0.y = vals[1]; o0.z = vals[2]; o0.w = vals[3];
    v4f o1; o1.x = vals[4]; o1.y = vals[5]; o1.z = vals[6]; o1.w = vals[7];
    v4f* dst = reinterpret_cast<v4f*>(out + (size_t)row * NEXP);
    __builtin_nontemporal_store(o0, dst);
    __builtin_nontemporal_store(o1, dst + 1);
}

extern "C" void kernel_launch(void* const* d_in, const int* in_sizes, int n_in,
                              void* d_out, int out_size, void* d_ws, size_t ws_size,
                              hipStream_t stream) {
    const float* x     = (const float*)d_in[0];
    const int*   label = (const int*)d_in[1];
    const float* w     = (const float*)d_in[2];
    const float* bg    = (const float*)d_in[3];
    float* out   = (float*)d_out;
    float* denom = (float*)d_ws;   // 8 floats

    (void)hipMemsetAsync(denom, 0, NEXP * sizeof(float), stream);
    gate_kernel<<<NBLOCKS, THREADS, 0, stream>>>(x, label, w, bg, out, denom);
    finalize_kernel<<<NROWS / 256, 256, 0, stream>>>(out, denom);
}